// Round 14
// baseline (145.009 us; speedup 1.0000x reference)
//
#include <hip/hip_runtime.h>

// VQ-VAE vector quantizer. N=131072 rows (32*64*64), D=64, K=512.
// X: NCHW f32 (32,64,64,64); W: (512,64) f32.
// out: [0]=loss, [1..8388609)=quantized NCHW, [8388609]=perplexity,
//      [8388610..)=one-hot encodings [131072][512].
#define BHW 262144
#define OUT_Q_OFF 1
#define OUT_P_OFF 8388609
#define OUT_E_OFF 8388610

// ws layout (4-byte words):
// [0..256)      loss partial slots (f32)   -- memset 0
// [768..1280)   wsq = ||e_k||^2 (f32)
// [1280..17664) bf16 codebook B-fragments, PRE-SCALED by -2: [tn=32][j=2][lane=64] x 8
// [17664..148736) per-row argmin indices (i32)
#define IDX_W 17664

typedef __attribute__((ext_vector_type(8))) short short8;
typedef __attribute__((ext_vector_type(4))) float f32x4;
typedef __attribute__((ext_vector_type(2))) float f32x2;

__device__ __forceinline__ unsigned short f2bf(float f) {
    union { float f; unsigned u; } c; c.f = f;
    unsigned r = (c.u + 0x7FFFu + ((c.u >> 16) & 1u)) >> 16;  // RNE
    return (unsigned short)r;
}

__global__ __launch_bounds__(512) void vq_init(const float* __restrict__ W, float* __restrict__ ws) {
    const int tid = blockIdx.x * 512 + threadIdx.x;
    if (tid < 512) {
        const float4* W4 = (const float4*)W;
        float s = 0.f;
#pragma unroll
        for (int i = 0; i < 16; ++i) {
            float4 v = W4[tid * 16 + i];
            s = fmaf(v.x, v.x, s); s = fmaf(v.y, v.y, s);
            s = fmaf(v.z, v.z, s); s = fmaf(v.w, v.w, s);
        }
        ws[768 + tid] = s;
    } else {
        const int c  = tid - 512;            // 0..4095
        const int l  = c & 63;
        const int j  = (c >> 6) & 1;
        const int tn = c >> 7;
        const int n  = tn * 16 + (l & 15);
        const int k0 = j * 32 + ((l >> 4) & 3) * 8;
        const float* src = W + n * 64 + k0;
        unsigned h0 = f2bf(-2.f * src[0]) | ((unsigned)f2bf(-2.f * src[1]) << 16);
        unsigned h1 = f2bf(-2.f * src[2]) | ((unsigned)f2bf(-2.f * src[3]) << 16);
        unsigned h2 = f2bf(-2.f * src[4]) | ((unsigned)f2bf(-2.f * src[5]) << 16);
        unsigned h3 = f2bf(-2.f * src[6]) | ((unsigned)f2bf(-2.f * src[7]) << 16);
        uint4* dst = (uint4*)(ws + 1280);
        dst[c] = make_uint4(h0, h1, h2, h3);
    }
}

// vq_main: R5 shape (1 wave/block, 16 rows, no LDS/barriers, 32 waves/CU) with
// ALL bulk output stores NON-TEMPORAL (bypass L2/L3 allocation) and ordered
// strictly AFTER every load. A/B vs R5/R10: isolates write-stream cache thrash.
__global__ __launch_bounds__(64) void vq_main(const float* __restrict__ X,
                                              const float* __restrict__ W,
                                              float* __restrict__ out,
                                              float* __restrict__ ws) {
    const int l    = threadIdx.x;        // 0..63
    const int nlow = l & 15;
    const int kg   = l >> 4;
    const int rowbase = blockIdx.x * 16; // 16 consecutive rows, same (b,h)
    const int b  = rowbase >> 12;
    const int h  = (rowbase >> 6) & 63;
    const int w0 = rowbase & 63;

    // ---- this lane's x row (A-frag row = nlow); all 16 loads in flight ----
    const float* xr = X + (size_t)b * BHW + (size_t)h * 64 + (w0 + nlow);
    float xf[16];
#pragma unroll
    for (int e = 0; e < 8; ++e) xf[e]     = xr[(size_t)(kg * 8 + e) * 4096];
#pragma unroll
    for (int e = 0; e < 8; ++e) xf[8 + e] = xr[(size_t)(32 + kg * 8 + e) * 4096];
    short8 a0, a1;
#pragma unroll
    for (int e = 0; e < 8; ++e) { a0[e] = (short)f2bf(xf[e]); a1[e] = (short)f2bf(xf[8 + e]); }

    // ---- scan all 512 codes: score = wsq (C-init) + (-2e)·x via MFMA ----
    const short8* __restrict__ B8  = (const short8*)(ws + 1280);
    const float*  __restrict__ wsq = ws + 768;
    float bS[4]; int bK[4];
#pragma unroll
    for (int r = 0; r < 4; ++r) { bS[r] = 3.4e38f; bK[r] = 0; }

#pragma unroll 4
    for (int tn = 0; tn < 32; ++tn) {
        short8 f0 = B8[tn * 128 + l];
        short8 f1 = B8[tn * 128 + 64 + l];
        const float wq = wsq[tn * 16 + nlow];
        f32x4 acc = {wq, wq, wq, wq};
        acc = __builtin_amdgcn_mfma_f32_16x16x32_bf16(a0, f0, acc, 0, 0, 0);
        acc = __builtin_amdgcn_mfma_f32_16x16x32_bf16(a1, f1, acc, 0, 0, 0);
        const int n = tn * 16 + nlow;
#pragma unroll
        for (int r = 0; r < 4; ++r) {
            if (acc[r] < bS[r]) { bS[r] = acc[r]; bK[r] = n; }
        }
    }
    // butterfly min-reduce over the 16 code-lanes per kg group (lowest-k tiebreak)
#pragma unroll
    for (int r = 0; r < 4; ++r) {
#pragma unroll
        for (int mask = 1; mask <= 8; mask <<= 1) {
            float os = __shfl_xor(bS[r], mask);
            int   ok = __shfl_xor(bK[r], mask);
            if (os < bS[r] || (os == bS[r] && ok < bK[r])) { bS[r] = os; bK[r] = ok; }
        }
    }

    // ---- own-row best via 4 shfl + select (row nlow lives in group nlow>>2, reg nlow&3) ----
    const int src = (nlow >> 2) * 16;
    const int sel = nlow & 3;
    int g0 = __shfl(bK[0], src), g1 = __shfl(bK[1], src);
    int g2 = __shfl(bK[2], src), g3 = __shfl(bK[3], src);
    const int rowBk = sel == 0 ? g0 : sel == 1 ? g1 : sel == 2 ? g2 : g3;

    // ---- W gathers for this row's code (LOADS BEFORE ANY BULK STORE) ----
    const float4* W4 = (const float4*)W;
    float4 q0 = W4[rowBk * 16 + kg * 2];
    float4 q1 = W4[rowBk * 16 + kg * 2 + 1];
    float4 q2 = W4[rowBk * 16 + 8 + kg * 2];
    float4 q3 = W4[rowBk * 16 + 8 + kg * 2 + 1];

    // idx store for fin histogram (lanes 0..15: row l's best == rowBk since nlow==l)
    if (l < 16) ((int*)ws)[IDX_W + rowbase + l] = rowBk;

    // ---- quantized_st + loss partials (NT stores; x register-resident) ----
    float qv[16] = {q0.x, q0.y, q0.z, q0.w, q1.x, q1.y, q1.z, q1.w,
                    q2.x, q2.y, q2.z, q2.w, q3.x, q3.y, q3.z, q3.w};
    float lsum = 0.f;
    float* op = out + OUT_Q_OFF + (size_t)b * BHW + (size_t)h * 64 + (w0 + nlow);
#pragma unroll
    for (int e = 0; e < 8; ++e) {
        float d0 = qv[e] - xf[e];
        lsum = fmaf(d0, d0, lsum);
        __builtin_nontemporal_store(xf[e] + d0, op + (size_t)(kg * 8 + e) * 4096);
        float d1 = qv[8 + e] - xf[8 + e];
        lsum = fmaf(d1, d1, lsum);
        __builtin_nontemporal_store(xf[8 + e] + d1, op + (size_t)(32 + kg * 8 + e) * 4096);
    }

    // ---- one-hot encodings, NT coalesced f32x2 stores (region 8B-aligned) ----
    f32x2* encB = (f32x2*)(out + OUT_E_OFF);
    const size_t Rbase = (size_t)rowbase;
#pragma unroll
    for (int m = 0; m < 16; ++m) {
        const int bkm = __shfl(bK[m & 3], (m >> 2) * 16);
        f32x2* erow = encB + (Rbase + m) * 256;
#pragma unroll
        for (int c = 0; c < 4; ++c) {
            const int p = c * 64 + l;
            f32x2 v;
            v.x = (bkm == 2 * p)     ? 1.f : 0.f;
            v.y = (bkm == 2 * p + 1) ? 1.f : 0.f;
            __builtin_nontemporal_store(v, erow + p);
        }
    }

    // ---- loss wave-reduce; spread atomics over 256 slots ----
#pragma unroll
    for (int off = 32; off >= 1; off >>= 1) lsum += __shfl_down(lsum, off);
    if (l == 0) atomicAdd(ws + (blockIdx.x & 255), lsum);
}

// vq_fin: single block. LDS histogram of 131072 indices, then finalize.
__global__ __launch_bounds__(512) void vq_fin(const float* __restrict__ ws, float* __restrict__ out) {
    __shared__ unsigned hist[512];
    __shared__ float redP[8], redL[8];
    const int t = threadIdx.x;
    hist[t] = 0u;
    __syncthreads();
    const uint4* __restrict__ idx4 = (const uint4*)((const int*)ws + IDX_W);
#pragma unroll 4
    for (int i = 0; i < 64; ++i) {
        uint4 v = idx4[i * 512 + t];
        atomicAdd(&hist[v.x], 1u);
        atomicAdd(&hist[v.y], 1u);
        atomicAdd(&hist[v.z], 1u);
        atomicAdd(&hist[v.w], 1u);
    }
    __syncthreads();
    float p = (float)hist[t] * (1.0f / 131072.0f);
    float s = p * logf(p + 1e-10f);
    float lp = (t < 256) ? ws[t] : 0.f;
#pragma unroll
    for (int off = 32; off >= 1; off >>= 1) {
        s  += __shfl_down(s, off);
        lp += __shfl_down(lp, off);
    }
    if ((t & 63) == 0) { redP[t >> 6] = s; redL[t >> 6] = lp; }
    __syncthreads();
    if (t == 0) {
        float tp = 0.f, tl = 0.f;
#pragma unroll
        for (int i = 0; i < 8; ++i) { tp += redP[i]; tl += redL[i]; }
        out[OUT_P_OFF] = expf(-tp);
        out[0] = tl * (1.25f / 8388608.0f);
    }
}

extern "C" void kernel_launch(void* const* d_in, const int* in_sizes, int n_in,
                              void* d_out, int out_size, void* d_ws, size_t ws_size,
                              hipStream_t stream) {
    const float* X = (const float*)d_in[0];
    const float* W = (const float*)d_in[1];
    float* out = (float*)d_out;
    float* ws  = (float*)d_ws;

    (void)hipMemsetAsync(d_ws, 0, 256 * sizeof(float), stream);   // loss slots
    vq_init<<<9, 512, 0, stream>>>(W, ws);
    vq_main<<<8192, 64, 0, stream>>>(X, W, out, ws);
    vq_fin<<<1, 512, 0, stream>>>(ws, out);
}

// Round 15
// 115.417 us; speedup vs baseline: 1.2564x; 1.2564x over previous
//
#include <hip/hip_runtime.h>

// VQ-VAE vector quantizer. N=131072 rows (32*64*64), D=64, K=512.
// X: NCHW f32 (32,64,64,64); W: (512,64) f32.
// out: [0]=loss, [1..8388609)=quantized NCHW, [8388609]=perplexity,
//      [8388610..)=one-hot encodings [131072][512].
#define BHW 262144
#define OUT_Q_OFF 1
#define OUT_P_OFF 8388609
#define OUT_E_OFF 8388610

// ws layout (4-byte words):
// [0..256)      loss partial slots (f32)   -- memset 0
// [768..1280)   wsq = ||e_k||^2 (f32)
// [1280..17664) bf16 codebook B-fragments, PRE-SCALED by -2: [tn=32][j=2][lane=64] x 8
// [17664..148736) per-row argmin indices (i32)
#define IDX_W 17664

typedef __attribute__((ext_vector_type(8))) short short8;
typedef __attribute__((ext_vector_type(4))) float f32x4;
typedef __attribute__((ext_vector_type(2))) float f32x2;

__device__ __forceinline__ unsigned short f2bf(float f) {
    union { float f; unsigned u; } c; c.f = f;
    unsigned r = (c.u + 0x7FFFu + ((c.u >> 16) & 1u)) >> 16;  // RNE
    return (unsigned short)r;
}

__global__ __launch_bounds__(512) void vq_init(const float* __restrict__ W, float* __restrict__ ws) {
    const int tid = blockIdx.x * 512 + threadIdx.x;
    if (tid < 512) {
        const float4* W4 = (const float4*)W;
        float s = 0.f;
#pragma unroll
        for (int i = 0; i < 16; ++i) {
            float4 v = W4[tid * 16 + i];
            s = fmaf(v.x, v.x, s); s = fmaf(v.y, v.y, s);
            s = fmaf(v.z, v.z, s); s = fmaf(v.w, v.w, s);
        }
        ws[768 + tid] = s;
    } else {
        const int c  = tid - 512;            // 0..4095
        const int l  = c & 63;
        const int j  = (c >> 6) & 1;
        const int tn = c >> 7;
        const int n  = tn * 16 + (l & 15);
        const int k0 = j * 32 + ((l >> 4) & 3) * 8;
        const float* src = W + n * 64 + k0;
        unsigned h0 = f2bf(-2.f * src[0]) | ((unsigned)f2bf(-2.f * src[1]) << 16);
        unsigned h1 = f2bf(-2.f * src[2]) | ((unsigned)f2bf(-2.f * src[3]) << 16);
        unsigned h2 = f2bf(-2.f * src[4]) | ((unsigned)f2bf(-2.f * src[5]) << 16);
        unsigned h3 = f2bf(-2.f * src[6]) | ((unsigned)f2bf(-2.f * src[7]) << 16);
        uint4* dst = (uint4*)(ws + 1280);
        dst[c] = make_uint4(h0, h1, h2, h3);
    }
}

// vq_main: 256 thr / 4 waves / 64 rows (one (b,h) w-line, w0==0).
// THIS ROUND: every bulk store is an ALIGNED 16B f32x4 (fillBuffer-style);
// the misaligned enc (+2 floats) and quantized (+1 float) regions are written
// on their interior aligned lattice, with tiny x2/scalar oddments.
__global__ __launch_bounds__(256) void vq_main(const float* __restrict__ X,
                                               const float* __restrict__ W,
                                               float* __restrict__ out,
                                               float* __restrict__ ws) {
    const int t    = threadIdx.x;
    const int l    = t & 63;
    const int wv   = t >> 6;
    const int nlow = l & 15;
    const int kg   = l >> 4;
    const int rowbase = blockIdx.x * 64;     // full w-line, shared (b,h)
    const int b = rowbase >> 12;
    const int h = (rowbase >> 6) & 63;
    const int myrow = wv * 16 + nlow;        // this lane's w

    __shared__ float xt[64 * 65];            // [c][w] tile, stride 65
    __shared__ int   best_lds[64];

    // ---- stage X tile: full-line contiguous float4 loads (R11-proven) ----
    const float4* __restrict__ X4 = (const float4*)X;
    const int base4 = b * 65536 + h * 16;    // float4 idx of [b][0][h][0]
#pragma unroll
    for (int i = 0; i < 4; ++i) {
        int flat = i * 256 + t;              // 0..1023
        int c  = flat >> 4;
        int w4 = flat & 15;
        float4 v = X4[base4 + c * 1024 + w4];
        int o = c * 65 + w4 * 4;
        xt[o] = v.x; xt[o + 1] = v.y; xt[o + 2] = v.z; xt[o + 3] = v.w;
    }
    __syncthreads();

    // ---- fragments from LDS ----
    float xf[16];
#pragma unroll
    for (int e = 0; e < 8; ++e) xf[e]     = xt[(kg * 8 + e) * 65 + myrow];
#pragma unroll
    for (int e = 0; e < 8; ++e) xf[8 + e] = xt[(32 + kg * 8 + e) * 65 + myrow];
    short8 a0, a1;
#pragma unroll
    for (int e = 0; e < 8; ++e) { a0[e] = (short)f2bf(xf[e]); a1[e] = (short)f2bf(xf[8 + e]); }

    // ---- scan all 512 codes ----
    const short8* __restrict__ B8  = (const short8*)(ws + 1280);
    const float*  __restrict__ wsq = ws + 768;
    float bS[4]; int bK[4];
#pragma unroll
    for (int r = 0; r < 4; ++r) { bS[r] = 3.4e38f; bK[r] = 0; }

#pragma unroll 4
    for (int tn = 0; tn < 32; ++tn) {
        short8 f0 = B8[tn * 128 + l];
        short8 f1 = B8[tn * 128 + 64 + l];
        const float wq = wsq[tn * 16 + nlow];
        f32x4 acc = {wq, wq, wq, wq};
        acc = __builtin_amdgcn_mfma_f32_16x16x32_bf16(a0, f0, acc, 0, 0, 0);
        acc = __builtin_amdgcn_mfma_f32_16x16x32_bf16(a1, f1, acc, 0, 0, 0);
        const int n = tn * 16 + nlow;
#pragma unroll
        for (int r = 0; r < 4; ++r) {
            if (acc[r] < bS[r]) { bS[r] = acc[r]; bK[r] = n; }
        }
    }
#pragma unroll
    for (int r = 0; r < 4; ++r) {
#pragma unroll
        for (int mask = 1; mask <= 8; mask <<= 1) {
            float os = __shfl_xor(bS[r], mask);
            int   ok = __shfl_xor(bK[r], mask);
            if (os < bS[r] || (os == bS[r] && ok < bK[r])) { bS[r] = os; bK[r] = ok; }
        }
    }

    // ---- own-row best (row nlow lives in group nlow>>2, reg nlow&3) ----
    const int src = (nlow >> 2) * 16;
    const int sel = nlow & 3;
    int g0 = __shfl(bK[0], src), g1 = __shfl(bK[1], src);
    int g2 = __shfl(bK[2], src), g3 = __shfl(bK[3], src);
    const int rowBk = sel == 0 ? g0 : sel == 1 ? g1 : sel == 2 ? g2 : g3;
    if (l < 16) {
        best_lds[wv * 16 + l] = rowBk;
        ((int*)ws)[IDX_W + rowbase + wv * 16 + l] = rowBk;
    }

    // ---- W gather; quantized_st + loss in registers ----
    const float4* W4 = (const float4*)W;
    float4 q0 = W4[rowBk * 16 + kg * 2];
    float4 q1 = W4[rowBk * 16 + kg * 2 + 1];
    float4 q2 = W4[rowBk * 16 + 8 + kg * 2];
    float4 q3 = W4[rowBk * 16 + 8 + kg * 2 + 1];
    float qv[16] = {q0.x, q0.y, q0.z, q0.w, q1.x, q1.y, q1.z, q1.w,
                    q2.x, q2.y, q2.z, q2.w, q3.x, q3.y, q3.z, q3.w};
    float st[16];
    float lsum = 0.f;
#pragma unroll
    for (int e = 0; e < 16; ++e) {
        float d = qv[e] - xf[e];
        lsum = fmaf(d, d, lsum);
        st[e] = xf[e] + d;
    }
    __syncthreads();                         // all xt fragment reads complete
#pragma unroll
    for (int e = 0; e < 8; ++e) xt[(kg * 8 + e) * 65 + myrow]      = st[e];
#pragma unroll
    for (int e = 0; e < 8; ++e) xt[(32 + kg * 8 + e) * 65 + myrow] = st[8 + e];

    // loss wave-reduce while LDS settles
#pragma unroll
    for (int off = 32; off >= 1; off >>= 1) lsum += __shfl_down(lsum, off);
    if (l == 0) atomicAdd(ws + ((blockIdx.x * 4 + wv) & 255), lsum);
    __syncthreads();

    // ---- quantized write-out: aligned f32x4 lattice (w=3+4p), oddments scalar ----
    {
        float* qbase = out + OUT_Q_OFF + (size_t)b * BHW + (size_t)h * 64;
#pragma unroll
        for (int i = 0; i < 4; ++i) {
            int s = i * 256 + t;             // 0..1023, use 0..959
            if (s < 960) {
                int c   = (s * 4370) >> 16;  // s/15 exact for s<960
                int pos = s - c * 15;
                int w   = 3 + 4 * pos;       // 3..59 -> covers w 3..62
                const float* row = xt + c * 65 + w;
                f32x4 v = {row[0], row[1], row[2], row[3]};
                *(f32x4*)(qbase + (size_t)c * 4096 + w) = v;   // 16B aligned
            }
        }
        // oddments: w in {0,1,2,63} per c
        int c = t >> 2, j = t & 3;
        int w = (j == 3) ? 63 : j;
        qbase[(size_t)c * 4096 + w] = xt[c * 65 + w];
    }

    // ---- enc write-out: aligned f32x4 lattice over [R*512+2, R*512+32766) ----
    {
        float* encs = out + OUT_E_OFF + (size_t)rowbase * 512;   // row R col 0
#pragma unroll 8
        for (int i = 0; i < 32; ++i) {
            int k = i * 256 + t;             // 0..8191, use 0..8190
            if (k < 8191) {
                int f    = 2 + 4 * k;        // block-local float offset
                int rloc = f >> 9;
                int col  = f & 511;          // ≡2 mod 4
                int kb   = best_lds[rloc];
                f32x4 v;
                if (col == 510) {            // straddle into next row's cols {0,1}
                    int kb2 = best_lds[rloc + 1];
                    v.x = (kb  == 510) ? 1.f : 0.f;
                    v.y = (kb  == 511) ? 1.f : 0.f;
                    v.z = (kb2 == 0)   ? 1.f : 0.f;
                    v.w = (kb2 == 1)   ? 1.f : 0.f;
                } else {
                    v.x = (col     == kb) ? 1.f : 0.f;
                    v.y = (col + 1 == kb) ? 1.f : 0.f;
                    v.z = (col + 2 == kb) ? 1.f : 0.f;
                    v.w = (col + 3 == kb) ? 1.f : 0.f;
                }
                *(f32x4*)(encs + f) = v;     // 16B aligned (enc base ≡2 mod 4)
            }
        }
        if (t == 0) {                        // head: row R cols {0,1} (8B aligned)
            int kb = best_lds[0];
            f32x2 v; v.x = (kb == 0) ? 1.f : 0.f; v.y = (kb == 1) ? 1.f : 0.f;
            *(f32x2*)encs = v;
        } else if (t == 1) {                 // tail: row R+63 cols {510,511}
            int kb = best_lds[63];
            f32x2 v; v.x = (kb == 510) ? 1.f : 0.f; v.y = (kb == 511) ? 1.f : 0.f;
            *(f32x2*)(encs + 63 * 512 + 510) = v;
        }
    }
}

// vq_fin: single block. LDS histogram of 131072 indices, then finalize.
__global__ __launch_bounds__(512) void vq_fin(const float* __restrict__ ws, float* __restrict__ out) {
    __shared__ unsigned hist[512];
    __shared__ float redP[8], redL[8];
    const int t = threadIdx.x;
    hist[t] = 0u;
    __syncthreads();
    const uint4* __restrict__ idx4 = (const uint4*)((const int*)ws + IDX_W);
#pragma unroll 4
    for (int i = 0; i < 64; ++i) {
        uint4 v = idx4[i * 512 + t];
        atomicAdd(&hist[v.x], 1u);
        atomicAdd(&hist[v.y], 1u);
        atomicAdd(&hist[v.z], 1u);
        atomicAdd(&hist[v.w], 1u);
    }
    __syncthreads();
    float p = (float)hist[t] * (1.0f / 131072.0f);
    float s = p * logf(p + 1e-10f);
    float lp = (t < 256) ? ws[t] : 0.f;
#pragma unroll
    for (int off = 32; off >= 1; off >>= 1) {
        s  += __shfl_down(s, off);
        lp += __shfl_down(lp, off);
    }
    if ((t & 63) == 0) { redP[t >> 6] = s; redL[t >> 6] = lp; }
    __syncthreads();
    if (t == 0) {
        float tp = 0.f, tl = 0.f;
#pragma unroll
        for (int i = 0; i < 8; ++i) { tp += redP[i]; tl += redL[i]; }
        out[OUT_P_OFF] = expf(-tp);
        out[0] = tl * (1.25f / 8388608.0f);
    }
}

extern "C" void kernel_launch(void* const* d_in, const int* in_sizes, int n_in,
                              void* d_out, int out_size, void* d_ws, size_t ws_size,
                              hipStream_t stream) {
    const float* X = (const float*)d_in[0];
    const float* W = (const float*)d_in[1];
    float* out = (float*)d_out;
    float* ws  = (float*)d_ws;

    (void)hipMemsetAsync(d_ws, 0, 256 * sizeof(float), stream);   // loss slots
    vq_init<<<9, 512, 0, stream>>>(W, ws);
    vq_main<<<2048, 256, 0, stream>>>(X, W, out, ws);
    vq_fin<<<1, 512, 0, stream>>>(ws, out);
}